// Round 4
// baseline (41.550 us; speedup 1.0000x reference)
//
#include <hip/hip_runtime.h>

typedef __bf16 bf16x8 __attribute__((ext_vector_type(8)));
typedef float  f32x4  __attribute__((ext_vector_type(4)));

__device__ __forceinline__ unsigned short f2bf(float f) {
    unsigned int u = __float_as_uint(f);
    u += 0x7FFF + ((u >> 16) & 1);          // RNE
    return (unsigned short)(u >> 16);
}
__device__ __forceinline__ unsigned int pk2bf(float a, float b) {
    return (unsigned int)f2bf(a) | ((unsigned int)f2bf(b) << 16);
}

#define GLD_LDS16(gptr, lptr) \
    __builtin_amdgcn_global_load_lds((const __attribute__((address_space(1))) void*)(gptr), \
                                     (__attribute__((address_space(3))) void*)(lptr), 16, 0, 0)

// ============ kA: blocks [0,64)=small GEMM wcT=(wv@wp)^T inline-convert; [64,320)=partials ============
__global__ __launch_bounds__(256) void kA(const float* __restrict__ x,
                                          const float* __restrict__ w_attn,
                                          const float* __restrict__ w_proj,
                                          unsigned short* __restrict__ wcT,
                                          float* __restrict__ part)
{
    __shared__ unsigned short As[2][64 * 64];
    __shared__ unsigned short Bs[2][64 * 64];
    const int bid = blockIdx.x, tid = threadIdx.x;

    if (bid < 64) {
        const int bm = (bid >> 3) * 64, bn = (bid & 7) * 64;
        const int lane = tid & 63, w = tid >> 6, wm = w >> 1, wn = w & 1;
        const int arow = lane & 15, kg = lane >> 4;
        const int ir = tid >> 2;          // 0..63 (A: i-row, B: m-row)
        const int q  = tid & 3;           // 16-element column group

        int offA[2][2], offB[2][2];
        #pragma unroll
        for (int f = 0; f < 2; ++f)
            #pragma unroll
            for (int kk = 0; kk < 2; ++kk) {
                offA[f][kk] = (wm * 32 + f * 16 + arow) * 128 + (((kk * 4 + kg) ^ (arow & 7)) << 4);
                offB[f][kk] = (wn * 32 + f * 16 + arow) * 128 + (((kk * 4 + kg) ^ (arow & 7)) << 4);
            }

        f32x4 acc[2][2] = {};
        float4 aR[4], bR[4];

        auto load_regs = [&](int kt) {
            const float* ap = w_attn + (size_t)(bm + ir) * 1536 + 1024 + kt * 64 + q * 16;
            #pragma unroll
            for (int u = 0; u < 4; ++u) aR[u] = *(const float4*)(ap + u * 4);
            const float* bp = w_proj + (size_t)(kt * 64 + ir) * 512 + bn + q * 16;
            #pragma unroll
            for (int u = 0; u < 4; ++u) bR[u] = *(const float4*)(bp + u * 4);
        };
        auto cvt_write = [&](int buf) {
            // A: row ir, chunks q*2, q*2+1 (16 bf16)
            uint4 lo, hi;
            lo.x = pk2bf(aR[0].x, aR[0].y); lo.y = pk2bf(aR[0].z, aR[0].w);
            lo.z = pk2bf(aR[1].x, aR[1].y); lo.w = pk2bf(aR[1].z, aR[1].w);
            hi.x = pk2bf(aR[2].x, aR[2].y); hi.y = pk2bf(aR[2].z, aR[2].w);
            hi.z = pk2bf(aR[3].x, aR[3].y); hi.w = pk2bf(aR[3].z, aR[3].w);
            char* a = (char*)As[buf] + ir * 128;
            *(uint4*)(a + (((q * 2    ) ^ (ir & 7)) << 4)) = lo;
            *(uint4*)(a + (((q * 2 + 1) ^ (ir & 7)) << 4)) = hi;
            // B: transpose w_proj tile: element (m=ir, j=q*16+s) -> Bs[j][m]
            char* bmem = (char*)Bs[buf];
            const float* br = (const float*)bR;
            #pragma unroll
            for (int s = 0; s < 16; ++s) {
                const int jl = q * 16 + s;
                *(unsigned short*)(bmem + jl * 128 + (((ir >> 3) ^ (jl & 7)) << 4) + (ir & 7) * 2)
                    = f2bf(br[s]);
            }
        };

        load_regs(0); cvt_write(0); __syncthreads();
        for (int kt = 0; kt < 8; ++kt) {
            const int buf = kt & 1;
            if (kt < 7) load_regs(kt + 1);
            const char* la = (const char*)As[buf];
            const char* lb = (const char*)Bs[buf];
            #pragma unroll
            for (int kk = 0; kk < 2; ++kk) {
                bf16x8 a0 = *(const bf16x8*)(la + offA[0][kk]);
                bf16x8 a1 = *(const bf16x8*)(la + offA[1][kk]);
                bf16x8 b0 = *(const bf16x8*)(lb + offB[0][kk]);
                bf16x8 b1 = *(const bf16x8*)(lb + offB[1][kk]);
                acc[0][0] = __builtin_amdgcn_mfma_f32_16x16x32_bf16(a0, b0, acc[0][0], 0, 0, 0);
                acc[0][1] = __builtin_amdgcn_mfma_f32_16x16x32_bf16(a0, b1, acc[0][1], 0, 0, 0);
                acc[1][0] = __builtin_amdgcn_mfma_f32_16x16x32_bf16(a1, b0, acc[1][0], 0, 0, 0);
                acc[1][1] = __builtin_amdgcn_mfma_f32_16x16x32_bf16(a1, b1, acc[1][1], 0, 0, 0);
            }
            __syncthreads();
            if (kt < 7) { cvt_write(buf ^ 1); __syncthreads(); }
        }
        #pragma unroll
        for (int fm = 0; fm < 2; ++fm)
            #pragma unroll
            for (int fn = 0; fn < 2; ++fn) {
                const int row0 = bm + wm * 32 + fm * 16 + kg * 4;
                const int col  = bn + wn * 32 + fn * 16 + arow;
                ushort4 pk;
                pk.x = f2bf(acc[fm][fn][0]);
                pk.y = f2bf(acc[fm][fn][1]);
                pk.z = f2bf(acc[fm][fn][2]);
                pk.w = f2bf(acc[fm][fn][3]);
                *(ushort4*)(&wcT[(size_t)col * 512 + row0]) = pk;   // C^T
            }
    } else {
        // partials: 256 blocks; chunk=64 rows split into two 32-row halves, j split in 2
        const int bb = bid - 64;              // 0..255
        const int ch = bb >> 2;               // global 64-row chunk 0..63
        const int th = (bb >> 1) & 1;         // t-half
        const int j  = (bb & 1) * 256 + tid;
        const float* p = x + ((size_t)ch * 64 + th * 32) * 512 + j;
        float s = 0.f;
        #pragma unroll 8
        for (int t = 0; t < 32; ++t) s += p[(size_t)t * 512];
        part[(size_t)(ch * 2 + th) * 512 + j] = s;
    }
}

// ============ kB: fused scan + big GEMM, A-tile resident, B dbuf counted-vmcnt ============
__global__ __launch_bounds__(256) void kB(const float* __restrict__ x,
                                          const unsigned short* __restrict__ wcT,
                                          const float* __restrict__ part,
                                          float* __restrict__ y)
{
    __shared__ unsigned short As[64 * 512];       // 64 KB, swizzled, resident
    __shared__ unsigned short Bs[2][64 * 64];     // 16 KB dbuf
    const int bid = blockIdx.x, tid = threadIdx.x;
    const int xcd = bid & 7, idx = bid >> 3;
    const int mt = xcd * 8 + (idx >> 3);          // 0..63  (XCD-chunked: m-panel per XCD)
    const int nt = idx & 7;                       // 0..7
    const int lane = tid & 63, w = tid >> 6, wm = w >> 1, wn = w & 1;
    const int arow = lane & 15, kg = lane >> 4;

    // --- issue B stages for kt0/kt1 immediately (lands under the scan prep)
    const int srow   = w * 16 + (lane >> 3);
    const int schunk = (lane & 7) ^ (lane >> 3);
    const unsigned short* gB0 = wcT + (size_t)(nt * 64 + srow) * 512 + schunk * 8;
    const unsigned short* gB1 = gB0 + (size_t)8 * 512;
    auto stageB = [&](int buf, int kt) {
        unsigned short* lb = Bs[buf];
        GLD_LDS16(gB0 + kt * 64, lb + (w * 16 + 0) * 64);
        GLD_LDS16(gB1 + kt * 64, lb + (w * 16 + 8) * 64);
    };
    stageB(0, 0);
    stageB(1, 1);

    // --- prefix from part (L2) + local 64-row cumsum of x -> bf16 A-tile in LDS
    const int b = mt >> 5, c = mt & 31;
    const int k0 = tid * 2;
    float rx = 0.f, ry = 0.f;
    for (int cc = 0; cc < 2 * c; ++cc) {          // 32-row partials, contiguous
        float2 p = *(const float2*)(part + ((size_t)b * 64 + cc) * 512 + k0);
        rx += p.x; ry += p.y;
    }
    {
        const float* xp = x + (size_t)mt * 64 * 512 + k0;
        const int chunkbase = tid >> 2;
        const int sub = (tid & 3) * 4;
        #pragma unroll 4
        for (int t = 0; t < 64; ++t) {
            float2 v = *(const float2*)(xp + (size_t)t * 512);
            rx += v.x; ry += v.y;
            const float inv = 1.0f / (float)(c * 64 + t + 1);
            *(unsigned int*)((char*)As + t * 1024 + ((chunkbase ^ (t & 7)) << 4) + sub)
                = pk2bf(rx * inv, ry * inv);
        }
    }
    asm volatile("s_waitcnt lgkmcnt(0)" ::: "memory");
    __builtin_amdgcn_s_barrier();

    int offA0[2][2], offB0[2][2];
    #pragma unroll
    for (int f = 0; f < 2; ++f)
        #pragma unroll
        for (int kk = 0; kk < 2; ++kk) {
            offA0[f][kk] = (wm * 32 + f * 16 + arow) * 1024 + (((kk * 4 + kg) ^ (arow & 7)) << 4);
            offB0[f][kk] = (wn * 32 + f * 16 + arow) * 128  + (((kk * 4 + kg) ^ (arow & 7)) << 4);
        }

    f32x4 acc[2][2] = {};
    #pragma unroll
    for (int kt = 0; kt < 8; ++kt) {
        const int buf = kt & 1;
        if (kt < 7) asm volatile("s_waitcnt vmcnt(2)" ::: "memory");   // kt's B landed; kt+1 in flight
        else        asm volatile("s_waitcnt vmcnt(0)" ::: "memory");
        __builtin_amdgcn_s_barrier();
        const char* la = (const char*)As + kt * 128;
        const char* lb = (const char*)Bs[buf];
        #pragma unroll
        for (int kk = 0; kk < 2; ++kk) {
            bf16x8 a0 = *(const bf16x8*)(la + offA0[0][kk]);
            bf16x8 a1 = *(const bf16x8*)(la + offA0[1][kk]);
            bf16x8 b0 = *(const bf16x8*)(lb + offB0[0][kk]);
            bf16x8 b1 = *(const bf16x8*)(lb + offB0[1][kk]);
            acc[0][0] = __builtin_amdgcn_mfma_f32_16x16x32_bf16(a0, b0, acc[0][0], 0, 0, 0);
            acc[0][1] = __builtin_amdgcn_mfma_f32_16x16x32_bf16(a0, b1, acc[0][1], 0, 0, 0);
            acc[1][0] = __builtin_amdgcn_mfma_f32_16x16x32_bf16(a1, b0, acc[1][0], 0, 0, 0);
            acc[1][1] = __builtin_amdgcn_mfma_f32_16x16x32_bf16(a1, b1, acc[1][1], 0, 0, 0);
        }
        __builtin_amdgcn_s_barrier();
        if (kt < 6) stageB(buf, kt + 2);          // overwrite just-consumed buffer
    }

    #pragma unroll
    for (int fm = 0; fm < 2; ++fm)
        #pragma unroll
        for (int fn = 0; fn < 2; ++fn) {
            const int row0 = mt * 64 + wm * 32 + fm * 16 + kg * 4;
            const int col  = nt * 64 + wn * 32 + fn * 16 + arow;
            #pragma unroll
            for (int r = 0; r < 4; ++r)
                y[(size_t)(row0 + r) * 512 + col] = acc[fm][fn][r];
        }
}

extern "C" void kernel_launch(void* const* d_in, const int* in_sizes, int n_in,
                              void* d_out, int out_size, void* d_ws, size_t ws_size,
                              hipStream_t stream)
{
    const float* x      = (const float*)d_in[0];   // (2,2048,512)
    const float* w_attn = (const float*)d_in[1];   // (512,1536); V = cols [1024,1536)
    const float* w_proj = (const float*)d_in[2];   // (512,512)
    float* y = (float*)d_out;

    unsigned short* wcT = (unsigned short*)d_ws;           // [512][512] bf16 ((wv@wp)^T)
    float* part = (float*)(wcT + 512 * 512);               // [128][512] f32 (32-row chunk sums)

    kA<<<320, 256, 0, stream>>>(x, w_attn, w_proj, wcT, part);
    kB<<<512, 256, 0, stream>>>(x, wcT, part, y);
}

// Round 5
// 41.399 us; speedup vs baseline: 1.0036x; 1.0036x over previous
//
#include <hip/hip_runtime.h>

typedef __bf16 bf16x8 __attribute__((ext_vector_type(8)));
typedef float  f32x4  __attribute__((ext_vector_type(4)));

__device__ __forceinline__ unsigned short f2bf(float f) {
    unsigned int u = __float_as_uint(f);
    u += 0x7FFF + ((u >> 16) & 1);          // RNE
    return (unsigned short)(u >> 16);
}
__device__ __forceinline__ unsigned int pk2bf(float a, float b) {
    return (unsigned int)f2bf(a) | ((unsigned int)f2bf(b) << 16);
}

#define GLD_LDS16(gptr, lptr) \
    __builtin_amdgcn_global_load_lds((const __attribute__((address_space(1))) void*)(gptr), \
                                     (__attribute__((address_space(3))) void*)(lptr), 16, 0, 0)

// ===== K1: blocks [0,64) small GEMM wcT=(wv@wp)^T with inline fp32->bf16 convert;
//           blocks [64,192) partial sums (32-row chunks, float2/thread = full row)
__global__ __launch_bounds__(256) void k1_gemm_partial(
    const float* __restrict__ x, const float* __restrict__ w_attn,
    const float* __restrict__ w_proj,
    unsigned short* __restrict__ wcT, float* __restrict__ part)
{
    __shared__ unsigned short As[2][64 * 64];
    __shared__ unsigned short Bs[2][64 * 64];
    const int bid = blockIdx.x, tid = threadIdx.x;

    if (bid < 64) {
        const int bm = (bid >> 3) * 64, bn = (bid & 7) * 64;
        const int lane = tid & 63, w = tid >> 6, wm = w >> 1, wn = w & 1;
        const int arow = lane & 15, kg = lane >> 4;
        const int ir = tid >> 2;          // 0..63
        const int q  = tid & 3;           // 16-col group

        int offA[2][2], offB[2][2];
        #pragma unroll
        for (int f = 0; f < 2; ++f)
            #pragma unroll
            for (int kk = 0; kk < 2; ++kk) {
                offA[f][kk] = (wm * 32 + f * 16 + arow) * 128 + (((kk * 4 + kg) ^ (arow & 7)) << 4);
                offB[f][kk] = (wn * 32 + f * 16 + arow) * 128 + (((kk * 4 + kg) ^ (arow & 7)) << 4);
            }

        f32x4 acc[2][2] = {};
        float4 aR[4], bR[4];

        auto load_regs = [&](int kt) {
            const float* ap = w_attn + (size_t)(bm + ir) * 1536 + 1024 + kt * 64 + q * 16;
            #pragma unroll
            for (int u = 0; u < 4; ++u) aR[u] = *(const float4*)(ap + u * 4);
            const float* bp = w_proj + (size_t)(kt * 64 + ir) * 512 + bn + q * 16;
            #pragma unroll
            for (int u = 0; u < 4; ++u) bR[u] = *(const float4*)(bp + u * 4);
        };
        auto cvt_write = [&](int buf) {
            uint4 lo, hi;
            lo.x = pk2bf(aR[0].x, aR[0].y); lo.y = pk2bf(aR[0].z, aR[0].w);
            lo.z = pk2bf(aR[1].x, aR[1].y); lo.w = pk2bf(aR[1].z, aR[1].w);
            hi.x = pk2bf(aR[2].x, aR[2].y); hi.y = pk2bf(aR[2].z, aR[2].w);
            hi.z = pk2bf(aR[3].x, aR[3].y); hi.w = pk2bf(aR[3].z, aR[3].w);
            char* a = (char*)As[buf] + ir * 128;
            *(uint4*)(a + (((q * 2    ) ^ (ir & 7)) << 4)) = lo;
            *(uint4*)(a + (((q * 2 + 1) ^ (ir & 7)) << 4)) = hi;
            char* bmem = (char*)Bs[buf];
            const float* br = (const float*)bR;
            #pragma unroll
            for (int s = 0; s < 16; ++s) {
                const int jl = q * 16 + s;
                *(unsigned short*)(bmem + jl * 128 + (((ir >> 3) ^ (jl & 7)) << 4) + (ir & 7) * 2)
                    = f2bf(br[s]);
            }
        };

        load_regs(0); cvt_write(0); __syncthreads();
        for (int kt = 0; kt < 8; ++kt) {
            const int buf = kt & 1;
            if (kt < 7) load_regs(kt + 1);
            const char* la = (const char*)As[buf];
            const char* lb = (const char*)Bs[buf];
            #pragma unroll
            for (int kk = 0; kk < 2; ++kk) {
                bf16x8 a0 = *(const bf16x8*)(la + offA[0][kk]);
                bf16x8 a1 = *(const bf16x8*)(la + offA[1][kk]);
                bf16x8 b0 = *(const bf16x8*)(lb + offB[0][kk]);
                bf16x8 b1 = *(const bf16x8*)(lb + offB[1][kk]);
                acc[0][0] = __builtin_amdgcn_mfma_f32_16x16x32_bf16(a0, b0, acc[0][0], 0, 0, 0);
                acc[0][1] = __builtin_amdgcn_mfma_f32_16x16x32_bf16(a0, b1, acc[0][1], 0, 0, 0);
                acc[1][0] = __builtin_amdgcn_mfma_f32_16x16x32_bf16(a1, b0, acc[1][0], 0, 0, 0);
                acc[1][1] = __builtin_amdgcn_mfma_f32_16x16x32_bf16(a1, b1, acc[1][1], 0, 0, 0);
            }
            __syncthreads();
            if (kt < 7) { cvt_write(buf ^ 1); __syncthreads(); }
        }
        #pragma unroll
        for (int fm = 0; fm < 2; ++fm)
            #pragma unroll
            for (int fn = 0; fn < 2; ++fn) {
                const int row0 = bm + wm * 32 + fm * 16 + kg * 4;
                const int col  = bn + wn * 32 + fn * 16 + arow;
                ushort4 pk;
                pk.x = f2bf(acc[fm][fn][0]);
                pk.y = f2bf(acc[fm][fn][1]);
                pk.z = f2bf(acc[fm][fn][2]);
                pk.w = f2bf(acc[fm][fn][3]);
                *(ushort4*)(&wcT[(size_t)col * 512 + row0]) = pk;   // C^T
            }
    } else {
        // partials: 128 blocks, chunk g = 32 rows, thread covers 2 cols (full row/block)
        const int g  = bid - 64;
        const int k0 = tid * 2;
        const float* p = x + (size_t)g * 32 * 512 + k0;
        float rx = 0.f, ry = 0.f;
        #pragma unroll 8
        for (int t = 0; t < 32; ++t) {
            float2 v = *(const float2*)(p + (size_t)t * 512);
            rx += v.x; ry += v.y;
        }
        *(float2*)(part + (size_t)g * 512 + k0) = make_float2(rx, ry);
    }
}

// ===== K2: finalize — prefix over part (L2) + 32-row running mean -> s16 bf16
__global__ __launch_bounds__(256) void k2_finalize(
    const float* __restrict__ x, const float* __restrict__ part,
    unsigned short* __restrict__ s16)
{
    const int g  = blockIdx.x;            // 0..127 global 32-row chunk
    const int b  = g >> 6, c = g & 63;
    const int k0 = threadIdx.x * 2;
    float rx = 0.f, ry = 0.f;
    for (int cc = 0; cc < c; ++cc) {
        float2 v = *(const float2*)(part + ((size_t)b * 64 + cc) * 512 + k0);
        rx += v.x; ry += v.y;
    }
    const float* xp = x + (size_t)g * 32 * 512 + k0;
    #pragma unroll 4
    for (int t = 0; t < 32; ++t) {
        float2 v = *(const float2*)(xp + (size_t)t * 512);
        rx += v.x; ry += v.y;
        const float inv = 1.0f / (float)(c * 32 + t + 1);
        *(unsigned int*)(s16 + (size_t)(g * 32 + t) * 512 + k0) = pk2bf(rx * inv, ry * inv);
    }
}

// ===== K3: y = s16 @ wcT^T (4096x512x512), dbuf + counted vmcnt, XCD-chunked swizzle
__global__ __launch_bounds__(256) void k3_biggemm(
    const unsigned short* __restrict__ s16,
    const unsigned short* __restrict__ wcT,
    float* __restrict__ y)
{
    __shared__ unsigned short As[2][64 * 64];
    __shared__ unsigned short Bs[2][64 * 64];
    const int bid = blockIdx.x;             // 0..511
    const int xcd = bid & 7, idx = bid >> 3;
    const int mt = xcd * 8 + (idx >> 3);    // contiguous m-panel per XCD
    const int nt = idx & 7;
    const int tid  = threadIdx.x;
    const int lane = tid & 63, w = tid >> 6, wm = w >> 1, wn = w & 1;
    const int arow = lane & 15, kg = lane >> 4;

    const int srow   = w * 16 + (lane >> 3);
    const int schunk = (lane & 7) ^ (lane >> 3);
    const unsigned short* gA0 = s16 + (size_t)(mt * 64 + srow    ) * 512 + schunk * 8;
    const unsigned short* gA1 = s16 + (size_t)(mt * 64 + srow + 8) * 512 + schunk * 8;
    const unsigned short* gB0 = wcT + (size_t)(nt * 64 + srow    ) * 512 + schunk * 8;
    const unsigned short* gB1 = wcT + (size_t)(nt * 64 + srow + 8) * 512 + schunk * 8;

    auto stage = [&](int buf, int kt) {
        const int k0 = kt * 64;
        GLD_LDS16(gA0 + k0, As[buf] + (w * 16 + 0) * 64);
        GLD_LDS16(gA1 + k0, As[buf] + (w * 16 + 8) * 64);
        GLD_LDS16(gB0 + k0, Bs[buf] + (w * 16 + 0) * 64);
        GLD_LDS16(gB1 + k0, Bs[buf] + (w * 16 + 8) * 64);
    };

    int offA[2][2], offB[2][2];
    #pragma unroll
    for (int f = 0; f < 2; ++f)
        #pragma unroll
        for (int kk = 0; kk < 2; ++kk) {
            offA[f][kk] = (wm * 32 + f * 16 + arow) * 128 + (((kk * 4 + kg) ^ (arow & 7)) << 4);
            offB[f][kk] = (wn * 32 + f * 16 + arow) * 128 + (((kk * 4 + kg) ^ (arow & 7)) << 4);
        }

    stage(0, 0);

    f32x4 acc[2][2] = {};
    #pragma unroll
    for (int kt = 0; kt < 8; ++kt) {
        const int buf = kt & 1;
        if (kt < 7) {
            stage(buf ^ 1, kt + 1);                              // kt+1 in flight
            asm volatile("s_waitcnt vmcnt(4)" ::: "memory");     // kt's 4 landed
        } else {
            asm volatile("s_waitcnt vmcnt(0)" ::: "memory");
        }
        __builtin_amdgcn_s_barrier();
        const char* la = (const char*)As[buf];
        const char* lb = (const char*)Bs[buf];
        #pragma unroll
        for (int kk = 0; kk < 2; ++kk) {
            bf16x8 a0 = *(const bf16x8*)(la + offA[0][kk]);
            bf16x8 a1 = *(const bf16x8*)(la + offA[1][kk]);
            bf16x8 b0 = *(const bf16x8*)(lb + offB[0][kk]);
            bf16x8 b1 = *(const bf16x8*)(lb + offB[1][kk]);
            acc[0][0] = __builtin_amdgcn_mfma_f32_16x16x32_bf16(a0, b0, acc[0][0], 0, 0, 0);
            acc[0][1] = __builtin_amdgcn_mfma_f32_16x16x32_bf16(a0, b1, acc[0][1], 0, 0, 0);
            acc[1][0] = __builtin_amdgcn_mfma_f32_16x16x32_bf16(a1, b0, acc[1][0], 0, 0, 0);
            acc[1][1] = __builtin_amdgcn_mfma_f32_16x16x32_bf16(a1, b1, acc[1][1], 0, 0, 0);
        }
        __builtin_amdgcn_s_barrier();                            // reads done before overwrite
    }

    #pragma unroll
    for (int fm = 0; fm < 2; ++fm)
        #pragma unroll
        for (int fn = 0; fn < 2; ++fn) {
            const int row0 = mt * 64 + wm * 32 + fm * 16 + kg * 4;
            const int col  = nt * 64 + wn * 32 + fn * 16 + arow;
            #pragma unroll
            for (int r = 0; r < 4; ++r)
                y[(size_t)(row0 + r) * 512 + col] = acc[fm][fn][r];
        }
}

extern "C" void kernel_launch(void* const* d_in, const int* in_sizes, int n_in,
                              void* d_out, int out_size, void* d_ws, size_t ws_size,
                              hipStream_t stream)
{
    const float* x      = (const float*)d_in[0];   // (2,2048,512)
    const float* w_attn = (const float*)d_in[1];   // (512,1536); V = cols [1024,1536)
    const float* w_proj = (const float*)d_in[2];   // (512,512)
    float* y = (float*)d_out;

    unsigned short* wcT = (unsigned short*)d_ws;           // [512][512] bf16 ((wv@wp)^T)
    unsigned short* s16 = wcT + 512 * 512;                 // [4096][512] bf16
    float* part = (float*)(s16 + (size_t)4096 * 512);      // [128][512] f32

    k1_gemm_partial<<<192, 256, 0, stream>>>(x, w_attn, w_proj, wcT, part);
    k2_finalize<<<128, 256, 0, stream>>>(x, part, s16);
    k3_biggemm<<<512, 256, 0, stream>>>(s16, wcT, y);
}

// Round 6
// 25.820 us; speedup vs baseline: 1.6092x; 1.6034x over previous
//
#include <hip/hip_runtime.h>

typedef __bf16 bf16x8 __attribute__((ext_vector_type(8)));
typedef float  f32x4  __attribute__((ext_vector_type(4)));

__device__ __forceinline__ unsigned short f2bf(float f) {
    unsigned int u = __float_as_uint(f);
    u += 0x7FFF + ((u >> 16) & 1);          // RNE
    return (unsigned short)(u >> 16);
}

#define GLD_LDS16(gptr, lptr) \
    __builtin_amdgcn_global_load_lds((const __attribute__((address_space(1))) void*)(gptr), \
                                     (__attribute__((address_space(3))) void*)(lptr), 16, 0, 0)

// ---- 64x64-tile bf16 GEMM body: C[m][n] = sum_k A[m][k]*Bt[n][k], K=512, ld=512.
// EPI=0: Cout=float[M][512] row-major. EPI=1: Cout=bf16 [512][512] transposed (C^T).
template<int EPI>
__device__ __forceinline__ void gemm_tile(const unsigned short* __restrict__ A,
                                          const unsigned short* __restrict__ Bt,
                                          void* __restrict__ Cout,
                                          unsigned short* lds,   // 2*2*4096 ushorts
                                          int bm, int bn)
{
    const int tid  = threadIdx.x;
    const int lane = tid & 63;
    const int w    = tid >> 6;
    const int wm   = w >> 1, wn = w & 1;

    const int srow   = w * 16 + (lane >> 3);
    const int schunk = (lane & 7) ^ (lane >> 3);    // inverse-swizzle on SOURCE
    const unsigned short* gA0 = A  + (size_t)(bm + srow    ) * 512 + schunk * 8;
    const unsigned short* gA1 = A  + (size_t)(bm + srow + 8) * 512 + schunk * 8;
    const unsigned short* gB0 = Bt + (size_t)(bn + srow    ) * 512 + schunk * 8;
    const unsigned short* gB1 = Bt + (size_t)(bn + srow + 8) * 512 + schunk * 8;

    const int arow = lane & 15;
    const int kg   = lane >> 4;
    int offA[2][2], offB[2][2];
    #pragma unroll
    for (int f = 0; f < 2; ++f)
        #pragma unroll
        for (int kk = 0; kk < 2; ++kk) {
            offA[f][kk] = (wm * 32 + f * 16 + arow) * 128 + (((kk * 4 + kg) ^ (arow & 7)) << 4);
            offB[f][kk] = (wn * 32 + f * 16 + arow) * 128 + (((kk * 4 + kg) ^ (arow & 7)) << 4);
        }

    f32x4 acc[2][2] = {};

    auto stage = [&](int buf, int kt) {
        const int k0 = kt * 64;
        unsigned short* la = lds + buf * 8192;
        unsigned short* lb = la + 4096;
        GLD_LDS16(gA0 + k0, la + (w * 16 + 0) * 64);
        GLD_LDS16(gA1 + k0, la + (w * 16 + 8) * 64);
        GLD_LDS16(gB0 + k0, lb + (w * 16 + 0) * 64);
        GLD_LDS16(gB1 + k0, lb + (w * 16 + 8) * 64);
    };

    stage(0, 0);
    asm volatile("s_waitcnt vmcnt(0)" ::: "memory");
    __syncthreads();

    #pragma unroll
    for (int kt = 0; kt < 8; ++kt) {
        const int buf = kt & 1;
        if (kt < 7) stage(buf ^ 1, kt + 1);
        const char* la = (const char*)(lds + buf * 8192);
        const char* lb = la + 8192;
        #pragma unroll
        for (int kk = 0; kk < 2; ++kk) {
            bf16x8 a0 = *(const bf16x8*)(la + offA[0][kk]);
            bf16x8 a1 = *(const bf16x8*)(la + offA[1][kk]);
            bf16x8 b0 = *(const bf16x8*)(lb + offB[0][kk]);
            bf16x8 b1 = *(const bf16x8*)(lb + offB[1][kk]);
            acc[0][0] = __builtin_amdgcn_mfma_f32_16x16x32_bf16(a0, b0, acc[0][0], 0, 0, 0);
            acc[0][1] = __builtin_amdgcn_mfma_f32_16x16x32_bf16(a0, b1, acc[0][1], 0, 0, 0);
            acc[1][0] = __builtin_amdgcn_mfma_f32_16x16x32_bf16(a1, b0, acc[1][0], 0, 0, 0);
            acc[1][1] = __builtin_amdgcn_mfma_f32_16x16x32_bf16(a1, b1, acc[1][1], 0, 0, 0);
        }
        asm volatile("s_waitcnt vmcnt(0)" ::: "memory");
        __syncthreads();
    }

    #pragma unroll
    for (int fm = 0; fm < 2; ++fm)
        #pragma unroll
        for (int fn = 0; fn < 2; ++fn) {
            const int row0 = bm + wm * 32 + fm * 16 + kg * 4;
            const int col  = bn + wn * 32 + fn * 16 + arow;
            if (EPI == 0) {
                float* C = (float*)Cout;
                #pragma unroll
                for (int r = 0; r < 4; ++r)
                    C[(size_t)(row0 + r) * 512 + col] = acc[fm][fn][r];
            } else {
                unsigned short* C = (unsigned short*)Cout;   // C^T
                ushort4 pk;
                pk.x = f2bf(acc[fm][fn][0]);
                pk.y = f2bf(acc[fm][fn][1]);
                pk.z = f2bf(acc[fm][fn][2]);
                pk.w = f2bf(acc[fm][fn][3]);
                *(ushort4*)(&C[(size_t)col * 512 + row0]) = pk;
            }
        }
}

// K1: blocks [0,64)   : LDS-tiled transpose w_proj -> wpT bf16
//     blocks [64,128) : w_attn V-slice -> wv bf16
//     blocks [128,384): partial_sums of x into part
__global__ __launch_bounds__(256) void k1_prep_partial(
    const float* __restrict__ x, const float* __restrict__ w_attn,
    const float* __restrict__ w_proj,
    unsigned short* __restrict__ wv, unsigned short* __restrict__ wpT,
    float* __restrict__ part)
{
    __shared__ float ls[64][65];
    const int bid = blockIdx.x, tid = threadIdx.x;

    if (bid < 64) {
        const int m0 = (bid >> 3) * 64;       // row block of w_proj
        const int j0 = (bid & 7) * 64;        // col block
        const int rr = tid >> 4;              // 0..15
        const int c4 = (tid & 15) * 4;
        #pragma unroll
        for (int i = 0; i < 4; ++i) {
            float4 v = *(const float4*)(w_proj + (size_t)(m0 + rr + 16 * i) * 512 + j0 + c4);
            ls[rr + 16 * i][c4 + 0] = v.x;
            ls[rr + 16 * i][c4 + 1] = v.y;
            ls[rr + 16 * i][c4 + 2] = v.z;
            ls[rr + 16 * i][c4 + 3] = v.w;
        }
        __syncthreads();
        const int c    = tid >> 2;            // 0..63 (j within tile)
        const int mgrp = (tid & 3) * 16;
        #pragma unroll
        for (int u = 0; u < 4; ++u) {
            const int m = mgrp + u * 4;
            ushort4 o;
            o.x = f2bf(ls[m + 0][c]);
            o.y = f2bf(ls[m + 1][c]);
            o.z = f2bf(ls[m + 2][c]);
            o.w = f2bf(ls[m + 3][c]);
            *(ushort4*)(wpT + (size_t)(j0 + c) * 512 + m0 + m) = o;
        }
    } else if (bid < 128) {
        const int bb = bid - 64;
        #pragma unroll
        for (int i = 0; i < 4; ++i) {
            const int flat = bb * 1024 + i * 256 + tid;   // float4 index in [512][128]
            const int ir = flat >> 7;
            const int m4 = (flat & 127) * 4;
            float4 v = *(const float4*)(w_attn + (size_t)ir * 1536 + 1024 + m4);
            ushort4 o;
            o.x = f2bf(v.x); o.y = f2bf(v.y); o.z = f2bf(v.z); o.w = f2bf(v.w);
            *(ushort4*)(wv + (size_t)ir * 512 + m4) = o;
        }
    } else {
        const int bx = bid - 128;             // 0..255
        const int b  = bx >> 7;
        const int ch = (bx >> 1) & 63;
        const int j  = (bx & 1) * 256 + tid;
        const float* p = x + ((size_t)b * 2048 + ch * 32) * 512 + j;
        float s = 0.f;
        #pragma unroll 8
        for (int t = 0; t < 32; ++t) s += p[(size_t)t * 512];
        part[((size_t)b * 64 + ch) * 512 + j] = s;
    }
}

// K2: blocks [0,64)  : small GEMM wcT = (wv @ wp)^T
//     blocks [64,320): finalize (masked fixed-trip prefix, fully pipelined) -> s16
__global__ __launch_bounds__(256) void k2_smallgemm_finalize(
    const float* __restrict__ x,
    const unsigned short* __restrict__ wv, const unsigned short* __restrict__ wpT,
    const float* __restrict__ part,
    unsigned short* __restrict__ wcT, unsigned short* __restrict__ s16)
{
    __shared__ unsigned short lds[2 * 2 * 4096];
    const int bid = blockIdx.x, tid = threadIdx.x;

    if (bid < 64) {
        gemm_tile<1>(wv, wpT, wcT, lds, (bid >> 3) * 64, (bid & 7) * 64);
    } else {
        const int bx = bid - 64;              // 0..255
        const int b  = bx >> 7;
        const int ch = (bx >> 1) & 63;
        const int j  = (bx & 1) * 256 + tid;
        // fixed-trip masked prefix: all 63 loads independent -> pipelined, not a
        // serial latency chain (prev: runtime-bound loop = load+wait+add per iter)
        float run = 0.f;
        #pragma unroll 8
        for (int cc = 0; cc < 63; ++cc) {
            float v = part[((size_t)b * 64 + cc) * 512 + j];
            run += (cc < ch) ? v : 0.f;
        }
        const float*    p = x   + ((size_t)b * 2048 + ch * 32) * 512 + j;
        unsigned short* q = s16 + ((size_t)b * 2048 + ch * 32) * 512 + j;
        #pragma unroll 8
        for (int t = 0; t < 32; ++t) {
            run += p[(size_t)t * 512];
            q[(size_t)t * 512] = f2bf(run * (1.0f / (float)(ch * 32 + t + 1)));
        }
    }
}

// K3: y = s16 @ wcT^T  (4096x512x512), XCD-chunked swizzle over 512 blocks
__global__ __launch_bounds__(256) void k3_biggemm(
    const unsigned short* __restrict__ s16,
    const unsigned short* __restrict__ wcT,
    float* __restrict__ y)
{
    __shared__ unsigned short lds[2 * 2 * 4096];
    const int bid  = blockIdx.x;            // 0..511
    const int xcd  = bid & 7;
    const int idx  = bid >> 3;              // 0..63
    const int vy   = xcd * 8 + (idx >> 3);  // m-tile 0..63
    const int vx   = idx & 7;               // n-tile 0..7
    gemm_tile<0>(s16, wcT, y, lds, vy * 64, vx * 64);
}

extern "C" void kernel_launch(void* const* d_in, const int* in_sizes, int n_in,
                              void* d_out, int out_size, void* d_ws, size_t ws_size,
                              hipStream_t stream)
{
    const float* x      = (const float*)d_in[0];   // (2,2048,512)
    const float* w_attn = (const float*)d_in[1];   // (512,1536); V = cols [1024,1536)
    const float* w_proj = (const float*)d_in[2];   // (512,512)
    float* y = (float*)d_out;

    unsigned short* wv  = (unsigned short*)d_ws;       // [512][512] bf16
    unsigned short* wpT = wv  + 512 * 512;             // [512][512] bf16 (w_proj^T)
    unsigned short* wcT = wpT + 512 * 512;             // [512][512] bf16 ((wv@wp)^T)
    unsigned short* s16 = wcT + 512 * 512;             // [4096][512] bf16
    float* part = (float*)(s16 + (size_t)4096 * 512);  // [2][64][512] f32

    k1_prep_partial<<<384, 256, 0, stream>>>(x, w_attn, w_proj, wv, wpT, part);
    k2_smallgemm_finalize<<<320, 256, 0, stream>>>(x, wv, wpT, part, wcT, s16);
    k3_biggemm<<<512, 256, 0, stream>>>(s16, wcT, y);
}